// Round 9
// baseline (109.690 us; speedup 1.0000x reference)
//
#include <hip/hip_runtime.h>
#include <hip/hip_bf16.h>

// B=128, LQ=32, LD=256, HID=768, DIM=128
typedef __attribute__((ext_vector_type(8))) short short8;
typedef __attribute__((ext_vector_type(4))) float f32x4;
typedef __attribute__((ext_vector_type(16))) float f32x16;

#define MFMA32(a, b, c) __builtin_amdgcn_mfma_f32_32x32x16_bf16(a, b, c, 0, 0, 0)

__device__ __forceinline__ short f2bf(float f) {
    union { float f; unsigned u; } x; x.f = f;
    unsigned r = x.u + 0x7fffu + ((x.u >> 16) & 1u);  // RNE
    return (short)(r >> 16);
}

__device__ __forceinline__ short8 cvt8(const float4& a, const float4& b) {
    short8 v;
    v[0]=f2bf(a.x); v[1]=f2bf(a.y); v[2]=f2bf(a.z); v[3]=f2bf(a.w);
    v[4]=f2bf(b.x); v[5]=f2bf(b.y); v[6]=f2bf(b.z); v[7]=f2bf(b.w);
    return v;
}

// ---------------------------------------------------------------------------
// Kernel 0 (unchanged): W [128x768] fp32 -> bf16 B-fragment image, 32x32x16.
// Slot gt = (kc*16 + ksub*4 + dt)*64 + lane holds 8 bf16 of B-frag:
//   dim = dt*32 + (lane&31),  k = kc*64 + ksub*16 + (lane>>5)*8 + j.
// ---------------------------------------------------------------------------
__global__ __launch_bounds__(256) void wprep_kernel(
    const float* __restrict__ W, unsigned short* __restrict__ Wimg)
{
    const int gt = blockIdx.x * 256 + threadIdx.x;    // 0..12287
    const int kc = gt >> 10, rem = gt & 1023;
    const int f = rem >> 6, lane = rem & 63;          // f = ksub*4 + dt
    const int ksub = f >> 2, dt = f & 3;
    const int dim = dt * 32 + (lane & 31);
    const int k0  = kc * 64 + ksub * 16 + (lane >> 5) * 8;
    const float4* s = reinterpret_cast<const float4*>(W + dim * 768 + k0);
    float4 a = s[0], b = s[1];
    *reinterpret_cast<short8*>(Wimg + (size_t)gt * 8) = cvt8(a, b);
}

// ---------------------------------------------------------------------------
// Kernel 1: P[row][dim] = l2norm(X[row] @ W^T), bf16 out.
// Block = 256 thr = 4 waves over ONE 32-row strip; wave dt computes dims
// dt*32..+32. 4608 waves total (4.5/SIMD) -> latency hidden by TLP.
// Per wave per chunk: 4 coalesced wf loads (L1/L2-hot) + 8 X loads (1-ahead
// prefetch, L1-dedup'd across the 4 waves) + 4 MFMA into one f32x16.
// Cross-wave norm combine via tiny LDS (2 barriers / block).
// ---------------------------------------------------------------------------
__global__ __launch_bounds__(256, 4) void proj_norm_kernel(
    const float* __restrict__ qh, const float* __restrict__ dh,
    const unsigned short* __restrict__ Wimg, const int* __restrict__ dmask,
    unsigned short* __restrict__ Qb, unsigned short* __restrict__ Db)
{
    __shared__ float ssb[4][32];
    __shared__ float rnb[32];

    const int tid = threadIdx.x;
    const int dt = tid >> 6;                    // wave id = dim-tile
    const int lane = tid & 63;
    const int lo5 = lane & 31, hi = lane >> 5;

    const int strip = blockIdx.x;               // Q: 0..127, D: 128..1151
    const bool isQ = strip < 128;
    const float* X = isQ ? qh : dh;
    const int prow = isQ ? strip * 32 : strip * 32 - 4096;

    const float* xp = X + (size_t)(prow + lo5) * 768 + hi * 8;  // lane-local row

    f32x16 acc = (f32x16)(0.0f);

    float4 xbuf[8];
    #pragma unroll
    for (int ks = 0; ks < 4; ++ks) {
        xbuf[2 * ks]     = *reinterpret_cast<const float4*>(xp + ks * 16);
        xbuf[2 * ks + 1] = *reinterpret_cast<const float4*>(xp + ks * 16 + 4);
    }

    for (int kc = 0; kc < 12; ++kc) {
        // this chunk's 4 W-fragments for this wave's dt (coalesced dwordx4)
        short8 wf[4];
        #pragma unroll
        for (int ksub = 0; ksub < 4; ++ksub)
            wf[ksub] = *reinterpret_cast<const short8*>(
                Wimg + ((size_t)(kc * 16 + ksub * 4 + dt) * 64 + lane) * 8);

        // convert current X (frees xbuf)
        short8 afr[4];
        #pragma unroll
        for (int ks = 0; ks < 4; ++ks) afr[ks] = cvt8(xbuf[2 * ks], xbuf[2 * ks + 1]);

        // next chunk's X (in flight across this chunk's MFMAs)
        if (kc < 11) {
            const float* nx = xp + (kc + 1) * 64;
            #pragma unroll
            for (int ks = 0; ks < 4; ++ks) {
                xbuf[2 * ks]     = *reinterpret_cast<const float4*>(nx + ks * 16);
                xbuf[2 * ks + 1] = *reinterpret_cast<const float4*>(nx + ks * 16 + 4);
            }
        }

        #pragma unroll
        for (int ksub = 0; ksub < 4; ++ksub)
            acc = MFMA32(afr[ksub], wf[ksub], acc);
    }

    // --- cross-wave L2 norm. acc[r] = C[row_local=(r&3)+8*(r>>2)+4*hi][dim=dt*32+lo5].
    // Butterfly over lo5 -> per-(row,dt) partial; LDS-combine the 4 dt waves.
    #pragma unroll
    for (int r = 0; r < 16; ++r) {
        float s = acc[r] * acc[r];
        s += __shfl_xor(s, 1);
        s += __shfl_xor(s, 2);
        s += __shfl_xor(s, 4);
        s += __shfl_xor(s, 8);
        s += __shfl_xor(s, 16);
        if (lo5 == 0) ssb[dt][(r & 3) + 8 * (r >> 2) + 4 * hi] = s;
    }
    __syncthreads();
    if (tid < 32) {
        float tot = ssb[0][tid] + ssb[1][tid] + ssb[2][tid] + ssb[3][tid];
        float rn = rsqrtf(tot);
        const int row = prow + tid;
        if (!isQ && dmask[row] == 0) rn = 0.f;   // zero masked doc tokens
        rnb[tid] = rn;
    }
    __syncthreads();

    unsigned short* P = isQ ? Qb : Db;
    #pragma unroll
    for (int r = 0; r < 16; ++r) {
        const int rl = (r & 3) + 8 * (r >> 2) + 4 * hi;
        const float rn = rnb[rl];
        P[(size_t)(prow + rl) * 128 + dt * 32 + lo5] = (unsigned short)f2bf(acc[r] * rn);
    }
}

// ---------------------------------------------------------------------------
// Kernel 1.5 (unchanged): in-place per-doc compaction of Db; valid rows first,
// padding duplicates token 0 (always valid; duplicates can't change a max).
// ---------------------------------------------------------------------------
__global__ __launch_bounds__(256) void compact_kernel(
    const int* __restrict__ dmask, unsigned short* __restrict__ Db)
{
    __shared__ __align__(16) short rows[256][128];
    __shared__ int wcnt[4];

    const int c = blockIdx.x;
    const int tid = threadIdx.x;
    const int wave = tid >> 6, lane = tid & 63;

    short8* ldsf = reinterpret_cast<short8*>(&rows[0][0]);
    const short8* src = reinterpret_cast<const short8*>(Db + (size_t)c * 256 * 128);
    #pragma unroll
    for (int i = 0; i < 16; ++i) {
        int idx = i * 256 + tid;
        int row = idx >> 4, ch = idx & 15;
        ldsf[row * 16 + (ch ^ (row & 15))] = src[idx];
    }

    const bool valid = dmask[c * 256 + tid] != 0;
    unsigned long long bal = __ballot(valid);
    const int before = __popcll(bal & ((1ull << lane) - 1ull));
    if (lane == 0) wcnt[wave] = __popcll(bal);
    __syncthreads();

    int base = 0, nv = 0;
    #pragma unroll
    for (int w = 0; w < 4; ++w) { int v = wcnt[w]; nv += v; if (w < wave) base += v; }
    const int myrank = valid ? (base + before) : (nv + (tid - base - before));
    const int srcrow = valid ? tid : 0;

    short8* dst = reinterpret_cast<short8*>(Db + (size_t)(c * 256 + myrank) * 128);
    #pragma unroll
    for (int i = 0; i < 16; ++i)
        dst[i] = *reinterpret_cast<const short8*>(&rows[srcrow][(i ^ (srcrow & 15)) * 8]);
}

// ---------------------------------------------------------------------------
// Kernel 2 (unchanged): out[b][c] = sum_q max_k Q[b,q,:] . Dc[c,k,:]
// Operand-swapped 32x32x16 (A=D tokens, B=Q): max over tokens is IN-LANE.
// ---------------------------------------------------------------------------
__global__ __launch_bounds__(512) void maxsim_kernel(
    const unsigned short* __restrict__ Qb, const unsigned short* __restrict__ Db,
    const int* __restrict__ dmask, float* __restrict__ out)
{
    __shared__ __align__(16) short Dlds[256][128];
    __shared__ int wcnt[4];

    const int tid = threadIdx.x;
    const int wave = tid >> 6, lane = tid & 63;
    const int lo5 = lane & 31, hi = lane >> 5;
    const int c  = blockIdx.x & 127;
    const int bg = blockIdx.x >> 7;
    const int b  = bg * 8 + wave;

    {
        const short8* src = reinterpret_cast<const short8*>(Db + (size_t)c * 256 * 128);
        #pragma unroll
        for (int i = 0; i < 8; ++i) {
            int idx = i * 512 + tid;
            int row = idx >> 4, ch = idx & 15;
            short8 v = src[row * 16 + (ch ^ (row & 15))];
            *reinterpret_cast<short8*>(&Dlds[row][ch * 8]) = v;
        }
    }
    if (tid < 256) {
        bool valid = dmask[c * 256 + tid] != 0;
        unsigned long long bal = __ballot(valid);
        if (lane == 0) wcnt[wave] = __popcll(bal);
    }
    __syncthreads();
    const int nv = wcnt[0] + wcnt[1] + wcnt[2] + wcnt[3];
    const int npairs = (nv + 63) >> 6;

    short8 a[8];
    const unsigned short* qp = Qb + ((size_t)b * 32 + lo5) * 128 + hi * 8;
    #pragma unroll
    for (int ks = 0; ks < 8; ++ks)
        a[ks] = *reinterpret_cast<const short8*>(qp + ks * 16);

    const int sw = lo5 & 15;
    float m = -1e30f;

    for (int p = 0; p < npairs; ++p) {
        f32x16 acc0 = (f32x16)(0.0f), acc1 = (f32x16)(0.0f);
        #pragma unroll
        for (int ks = 0; ks < 8; ++ks) {
            const int chs = ((2 * ks + hi) ^ sw) * 8;
            short8 d0 = *reinterpret_cast<const short8*>(&Dlds[p * 64 + lo5][chs]);
            short8 d1 = *reinterpret_cast<const short8*>(&Dlds[p * 64 + 32 + lo5][chs]);
            acc0 = MFMA32(d0, a[ks], acc0);
            acc1 = MFMA32(d1, a[ks], acc1);
        }
        #pragma unroll
        for (int r = 0; r < 16; ++r)
            m = fmaxf(m, fmaxf(acc0[r], acc1[r]));
    }

    m = fmaxf(m, __shfl_xor(m, 32));
    float s = m;
    s += __shfl_xor(s, 1);
    s += __shfl_xor(s, 2);
    s += __shfl_xor(s, 4);
    s += __shfl_xor(s, 8);
    s += __shfl_xor(s, 16);
    if (lane == 0) out[b * 128 + c] = s;
}

extern "C" void kernel_launch(void* const* d_in, const int* in_sizes, int n_in,
                              void* d_out, int out_size, void* d_ws, size_t ws_size,
                              hipStream_t stream)
{
    const float* qh    = (const float*)d_in[0];   // [128,32,768]
    const float* dh    = (const float*)d_in[1];   // [128,256,768]
    const float* W     = (const float*)d_in[2];   // [128,768]
    const int*   dmask = (const int*)d_in[3];     // [128,256]
    float* out = (float*)d_out;                   // [128,128]

    unsigned short* Qb   = (unsigned short*)d_ws;       // 4096x128 bf16 (1 MB)
    unsigned short* Db   = Qb + 4096 * 128;             // 32768x128 bf16 (8 MB)
    unsigned short* Wimg = Db + (size_t)32768 * 128;    // 12288x8 bf16 (196 KB)

    hipLaunchKernelGGL(wprep_kernel, dim3(48), dim3(256), 0, stream, W, Wimg);
    // 1152 strips of 32 rows; 4 dim-tile waves per strip
    hipLaunchKernelGGL(proj_norm_kernel, dim3(1152), dim3(256), 0, stream,
                       qh, dh, Wimg, dmask, Qb, Db);
    hipLaunchKernelGGL(compact_kernel, dim3(128), dim3(256), 0, stream,
                       dmask, Db);
    hipLaunchKernelGGL(maxsim_kernel, dim3(2048), dim3(512), 0, stream,
                       Qb, Db, dmask, out);
}

// Round 10
// 75.136 us; speedup vs baseline: 1.4599x; 1.4599x over previous
//
#include <hip/hip_runtime.h>
#include <hip/hip_bf16.h>

// B=128, LQ=32, LD=256, HID=768, DIM=128
typedef __attribute__((ext_vector_type(8))) short short8;
typedef __attribute__((ext_vector_type(4))) float f32x4;
typedef __attribute__((ext_vector_type(16))) float f32x16;

#define MFMA16(a, b, c) __builtin_amdgcn_mfma_f32_16x16x32_bf16(a, b, c, 0, 0, 0)
#define MFMA32(a, b, c) __builtin_amdgcn_mfma_f32_32x32x16_bf16(a, b, c, 0, 0, 0)

__device__ __forceinline__ short f2bf(float f) {
    union { float f; unsigned u; } x; x.f = f;
    unsigned r = x.u + 0x7fffu + ((x.u >> 16) & 1u);  // RNE
    return (short)(r >> 16);
}

__device__ __forceinline__ short8 cvt8(const float4& a, const float4& b) {
    short8 v;
    v[0]=f2bf(a.x); v[1]=f2bf(a.y); v[2]=f2bf(a.z); v[3]=f2bf(a.w);
    v[4]=f2bf(b.x); v[5]=f2bf(b.y); v[6]=f2bf(b.z); v[7]=f2bf(b.w);
    return v;
}

// ---------------------------------------------------------------------------
// Kernel 0: W [128x768] fp32 -> bf16 B-fragment image for 16x16x32 MFMA.
// Slot gt = (kc*16 + f)*64 + lane, f = ks*8 + dimt:
//   dim = (f&7)*16 + (lane&15),  k = kc*64 + (f>>3)*32 + (lane>>4)*8 + j.
// Per-K-chunk image is a LINEAR 16 KB block -> global_load_lds staging.
// ---------------------------------------------------------------------------
__global__ __launch_bounds__(256) void wprep_kernel(
    const float* __restrict__ W, unsigned short* __restrict__ Wimg)
{
    const int gt = blockIdx.x * 256 + threadIdx.x;    // 0..12287
    const int kc = gt >> 10, rem = gt & 1023;
    const int f = rem >> 6, lane = rem & 63;
    const int dim = (f & 7) * 16 + (lane & 15);
    const int kb  = kc * 64 + (f >> 3) * 32 + (lane >> 4) * 8;
    const float4* s = reinterpret_cast<const float4*>(W + dim * 768 + kb);
    float4 a = s[0], b = s[1];
    *reinterpret_cast<short8*>(Wimg + (size_t)gt * 8) = cvt8(a, b);
}

// ---------------------------------------------------------------------------
// Kernel 1: P[row][dim] = l2norm(X[row] @ W^T), bf16 out.
// T3-minimum 2-phase pipeline (proven template): BM=64, BK=64, 4 waves,
// wave = 32 rows x 64 dims (2x4 16x16 frags -> 2-way A/B reuse).
// W: global_load_lds from frag image (linear, dbuf). X: T14 split -
// load t+1 to regs BEFORE compute(t), cvt+ds_write AFTER (latency hidden).
// X LDS chunk-XOR swizzled (ch ^= row&7): A-frag reads conflict-free.
// ---------------------------------------------------------------------------
__global__ __launch_bounds__(256) void proj_norm_kernel(
    const float* __restrict__ qh, const float* __restrict__ dh,
    const unsigned short* __restrict__ Wimg, const int* __restrict__ dmask,
    unsigned short* __restrict__ Qb, unsigned short* __restrict__ Db)
{
    __shared__ __align__(16) short Xl[2][64][64];   // 16 KB (bf16, swizzled)
    __shared__ __align__(16) short Wl[2][8192];     // 32 KB (frag image, linear)
    __shared__ float ssb[4][32];

    const int tid = threadIdx.x;
    const int wave = tid >> 6, lane = tid & 63;
    const int l = lane & 15, g = lane >> 4;
    const int rw = (wave & 1) * 32;                 // wave's row base
    const int dn4 = (wave >> 1) * 4;                // wave's dim-tile base
    const int dn = dn4 * 16;

    const int rowbase = blockIdx.x * 64;            // Q: blocks 0..63, D: 64..575
    const bool isQ = rowbase < 4096;
    const float* X = isQ ? qh : dh;
    const int prow = isQ ? rowbase : rowbase - 4096;

    // X staging: thread -> row tid>>2, 16 floats (chunks (tid&3)*2, +1)
    const int xrow = tid >> 2, xc = (tid & 3) * 2;
    const float* xsrc = X + (size_t)(prow + xrow) * 768 + xc * 8;

    float4 xr[4];
    auto xload = [&](int t) {
        const float4* s = reinterpret_cast<const float4*>(xsrc + t * 64);
        xr[0] = s[0]; xr[1] = s[1]; xr[2] = s[2]; xr[3] = s[3];
    };
    auto xwrite = [&](int p) {
        const int c0 = xc ^ (xrow & 7), c1 = (xc + 1) ^ (xrow & 7);
        *reinterpret_cast<short8*>(&Xl[p][xrow][c0 * 8]) = cvt8(xr[0], xr[1]);
        *reinterpret_cast<short8*>(&Xl[p][xrow][c1 * 8]) = cvt8(xr[2], xr[3]);
    };
    auto wstage = [&](int kc, int p) {              // 4 x global_load_lds w16/wave
        const unsigned short* src = Wimg + (size_t)kc * 8192 + wave * 2048 + lane * 8;
        #pragma unroll
        for (int i = 0; i < 4; ++i)
            __builtin_amdgcn_global_load_lds(
                (const __attribute__((address_space(1))) void*)(src + i * 512),
                (__attribute__((address_space(3))) void*)(&Wl[p][wave * 2048 + i * 512]),
                16, 0, 0);
    };

    f32x4 acc[2][4];
    #pragma unroll
    for (int rt = 0; rt < 2; ++rt)
        #pragma unroll
        for (int n = 0; n < 4; ++n) acc[rt][n] = (f32x4)(0.0f);

    auto compute = [&](int p) {
        #pragma unroll
        for (int ks = 0; ks < 2; ++ks) {
            short8 af[2];
            #pragma unroll
            for (int rt = 0; rt < 2; ++rt) {
                const int row = rw + rt * 16 + l;
                const int ch = (4 * ks + g) ^ (row & 7);
                af[rt] = *reinterpret_cast<const short8*>(&Xl[p][row][ch * 8]);
            }
            #pragma unroll
            for (int n = 0; n < 4; ++n) {
                short8 bf = *reinterpret_cast<const short8*>(
                    &Wl[p][(ks * 8 + dn4 + n) * 512 + lane * 8]);
                acc[0][n] = MFMA16(af[0], bf, acc[0][n]);
                acc[1][n] = MFMA16(af[1], bf, acc[1][n]);
            }
        }
    };

    // prologue: tile 0
    xload(0); wstage(0, 0); xwrite(0);
    __syncthreads();

    for (int t = 0; t < 12; ++t) {
        const int p = t & 1;
        if (t < 11) { xload(t + 1); wstage(t + 1, p ^ 1); }  // issue early (T14)
        compute(p);
        if (t < 11) xwrite(p ^ 1);                            // write late
        __syncthreads();
    }

    // --- L2 norm: acc[rt][n][r] = C[row=rw+rt*16+g*4+r][dim=dn+n*16+l].
    // Butterfly over l sums this wave's 64 dims; ssb combines wave pairs.
    #pragma unroll
    for (int rt = 0; rt < 2; ++rt)
        #pragma unroll
        for (int r = 0; r < 4; ++r) {
            float s = 0.f;
            #pragma unroll
            for (int n = 0; n < 4; ++n) s += acc[rt][n][r] * acc[rt][n][r];
            s += __shfl_xor(s, 1);
            s += __shfl_xor(s, 2);
            s += __shfl_xor(s, 4);
            s += __shfl_xor(s, 8);
            if (l == 0) ssb[wave][rt * 16 + g * 4 + r] = s;
        }
    __syncthreads();

    unsigned short* P = isQ ? Qb : Db;
    #pragma unroll
    for (int rt = 0; rt < 2; ++rt)
        #pragma unroll
        for (int r = 0; r < 4; ++r) {
            const int idx = rt * 16 + g * 4 + r;
            const int row = prow + rw + idx;
            float rn = rsqrtf(ssb[wave][idx] + ssb[wave ^ 2][idx]);
            if (!isQ && dmask[row] == 0) rn = 0.f;   // zero masked doc tokens
            #pragma unroll
            for (int n = 0; n < 4; ++n)
                P[(size_t)row * 128 + dn + n * 16 + l] =
                    (unsigned short)f2bf(acc[rt][n][r] * rn);
        }
}

// ---------------------------------------------------------------------------
// Kernel 1.5 (unchanged): in-place per-doc compaction of Db; valid rows first,
// padding duplicates token 0 (always valid; duplicates can't change a max).
// ---------------------------------------------------------------------------
__global__ __launch_bounds__(256) void compact_kernel(
    const int* __restrict__ dmask, unsigned short* __restrict__ Db)
{
    __shared__ __align__(16) short rows[256][128];
    __shared__ int wcnt[4];

    const int c = blockIdx.x;
    const int tid = threadIdx.x;
    const int wave = tid >> 6, lane = tid & 63;

    short8* ldsf = reinterpret_cast<short8*>(&rows[0][0]);
    const short8* src = reinterpret_cast<const short8*>(Db + (size_t)c * 256 * 128);
    #pragma unroll
    for (int i = 0; i < 16; ++i) {
        int idx = i * 256 + tid;
        int row = idx >> 4, ch = idx & 15;
        ldsf[row * 16 + (ch ^ (row & 15))] = src[idx];
    }

    const bool valid = dmask[c * 256 + tid] != 0;
    unsigned long long bal = __ballot(valid);
    const int before = __popcll(bal & ((1ull << lane) - 1ull));
    if (lane == 0) wcnt[wave] = __popcll(bal);
    __syncthreads();

    int base = 0, nv = 0;
    #pragma unroll
    for (int w = 0; w < 4; ++w) { int v = wcnt[w]; nv += v; if (w < wave) base += v; }
    const int myrank = valid ? (base + before) : (nv + (tid - base - before));
    const int srcrow = valid ? tid : 0;

    short8* dst = reinterpret_cast<short8*>(Db + (size_t)(c * 256 + myrank) * 128);
    #pragma unroll
    for (int i = 0; i < 16; ++i)
        dst[i] = *reinterpret_cast<const short8*>(&rows[srcrow][(i ^ (srcrow & 15)) * 8]);
}

// ---------------------------------------------------------------------------
// Kernel 2 (unchanged): out[b][c] = sum_q max_k Q[b,q,:] . Dc[c,k,:]
// Operand-swapped 32x32x16 (A=D tokens, B=Q): max over tokens is IN-LANE.
// ---------------------------------------------------------------------------
__global__ __launch_bounds__(512) void maxsim_kernel(
    const unsigned short* __restrict__ Qb, const unsigned short* __restrict__ Db,
    const int* __restrict__ dmask, float* __restrict__ out)
{
    __shared__ __align__(16) short Dlds[256][128];
    __shared__ int wcnt[4];

    const int tid = threadIdx.x;
    const int wave = tid >> 6, lane = tid & 63;
    const int lo5 = lane & 31, hi = lane >> 5;
    const int c  = blockIdx.x & 127;
    const int bg = blockIdx.x >> 7;
    const int b  = bg * 8 + wave;

    {
        const short8* src = reinterpret_cast<const short8*>(Db + (size_t)c * 256 * 128);
        #pragma unroll
        for (int i = 0; i < 8; ++i) {
            int idx = i * 512 + tid;
            int row = idx >> 4, ch = idx & 15;
            short8 v = src[row * 16 + (ch ^ (row & 15))];
            *reinterpret_cast<short8*>(&Dlds[row][ch * 8]) = v;
        }
    }
    if (tid < 256) {
        bool valid = dmask[c * 256 + tid] != 0;
        unsigned long long bal = __ballot(valid);
        if (lane == 0) wcnt[wave] = __popcll(bal);
    }
    __syncthreads();
    const int nv = wcnt[0] + wcnt[1] + wcnt[2] + wcnt[3];
    const int npairs = (nv + 63) >> 6;

    short8 a[8];
    const unsigned short* qp = Qb + ((size_t)b * 32 + lo5) * 128 + hi * 8;
    #pragma unroll
    for (int ks = 0; ks < 8; ++ks)
        a[ks] = *reinterpret_cast<const short8*>(qp + ks * 16);

    const int sw = lo5 & 15;
    float m = -1e30f;

    for (int p = 0; p < npairs; ++p) {
        f32x16 acc0 = (f32x16)(0.0f), acc1 = (f32x16)(0.0f);
        #pragma unroll
        for (int ks = 0; ks < 8; ++ks) {
            const int chs = ((2 * ks + hi) ^ sw) * 8;
            short8 d0 = *reinterpret_cast<const short8*>(&Dlds[p * 64 + lo5][chs]);
            short8 d1 = *reinterpret_cast<const short8*>(&Dlds[p * 64 + 32 + lo5][chs]);
            acc0 = MFMA32(d0, a[ks], acc0);
            acc1 = MFMA32(d1, a[ks], acc1);
        }
        #pragma unroll
        for (int r = 0; r < 16; ++r)
            m = fmaxf(m, fmaxf(acc0[r], acc1[r]));
    }

    m = fmaxf(m, __shfl_xor(m, 32));
    float s = m;
    s += __shfl_xor(s, 1);
    s += __shfl_xor(s, 2);
    s += __shfl_xor(s, 4);
    s += __shfl_xor(s, 8);
    s += __shfl_xor(s, 16);
    if (lane == 0) out[b * 128 + c] = s;
}

extern "C" void kernel_launch(void* const* d_in, const int* in_sizes, int n_in,
                              void* d_out, int out_size, void* d_ws, size_t ws_size,
                              hipStream_t stream)
{
    const float* qh    = (const float*)d_in[0];   // [128,32,768]
    const float* dh    = (const float*)d_in[1];   // [128,256,768]
    const float* W     = (const float*)d_in[2];   // [128,768]
    const int*   dmask = (const int*)d_in[3];     // [128,256]
    float* out = (float*)d_out;                   // [128,128]

    unsigned short* Qb   = (unsigned short*)d_ws;       // 4096x128 bf16 (1 MB)
    unsigned short* Db   = Qb + 4096 * 128;             // 32768x128 bf16 (8 MB)
    unsigned short* Wimg = Db + (size_t)32768 * 128;    // 12288x8 bf16 (196 KB)

    hipLaunchKernelGGL(wprep_kernel, dim3(48), dim3(256), 0, stream, W, Wimg);
    // 576 blocks of 64 rows; all co-resident at 3 blocks/CU
    hipLaunchKernelGGL(proj_norm_kernel, dim3(576), dim3(256), 0, stream,
                       qh, dh, Wimg, dmask, Qb, Db);
    hipLaunchKernelGGL(compact_kernel, dim3(128), dim3(256), 0, stream,
                       dmask, Db);
    hipLaunchKernelGGL(maxsim_kernel, dim3(2048), dim3(512), 0, stream,
                       Qb, Db, dmask, out);
}